// Round 17
// baseline (65.209 us; speedup 1.0000x reference)
//
#include <hip/hip_runtime.h>
#include <hip/hip_bf16.h>

using frag_ab = __attribute__((ext_vector_type(8))) short;  // 8 bf16
using frag_cd = __attribute__((ext_vector_type(4))) float;  // 4 fp32

#define SLEN 1024
#define CDIM 256
#define KTOT 768  // 3 * 256
#define PD 8      // B-fragment prefetch ring depth (proven: ~120 VGPR live)

static __device__ __forceinline__ short f2bf(float f) {
    __hip_bfloat16 h = __float2bfloat16(f);
    return *reinterpret_cast<short*>(&h);
}

// ---------------------------------------------------------------------------
// Kernel 1: blocks 0..15: per-batch scan of d=round(target) -> src table;
//           blocks 16..399: repack both conv weights to Bt[f][k3*256+c] bf16
// ---------------------------------------------------------------------------
__global__ __launch_bounds__(1024) void scan_repack_kernel(
    const float* __restrict__ target, int* __restrict__ src, int T,
    const float* __restrict__ w1, __hip_bfloat16* __restrict__ bt1,
    const float* __restrict__ w2, __hip_bfloat16* __restrict__ bt2)
{
    __shared__ int waveSum[16];
    const int tid = threadIdx.x;

    if (blockIdx.x < 16) {
        const int b = blockIdx.x;
        for (int i = tid; i < T; i += 1024) src[b * T + i] = -1;

        const float tv = target[b * SLEN + tid];
        const int d = (int)rintf(tv);

        const int lane = tid & 63;
        const int wid = tid >> 6;
        int v = d;
#pragma unroll
        for (int off = 1; off < 64; off <<= 1) {
            int n = __shfl_up(v, off);
            if (lane >= off) v += n;
        }
        if (lane == 63) waveSum[wid] = v;
        __syncthreads();
        if (tid < 16) {
            int wv = waveSum[tid];
#pragma unroll
            for (int off = 1; off < 16; off <<= 1) {
                int n = __shfl_up(wv, off);
                if (tid >= off) wv += n;
            }
            waveSum[tid] = wv;
        }
        __syncthreads();
        const int fin = v + (wid > 0 ? waveSum[wid - 1] : 0);
        const int start = fin - d;
        for (int t = start; t < fin; ++t)
            if (t >= 0 && t < T) src[b * T + t] = tid;
    } else {
        const int id = (blockIdx.x - 16) * 1024 + tid;  // 0..393215
        const int which = id >= 196608;
        const int e = which ? id - 196608 : id;
        const int f = e / KTOT;
        const int K = e - f * KTOT;
        const int k3 = K >> 8;
        const int c = K & 255;
        const float* w = which ? w2 : w1;
        __hip_bfloat16* bt = which ? bt2 : bt1;
        bt[f * KTOT + K] = __float2bfloat16(w[f * KTOT + c * 3 + k3]);
    }
}

// ---------------------------------------------------------------------------
// Kernel 2: FUSED conv pipeline + expand, heterogeneous waves in ONE block.
//   waves 0..7  : R11-proven conv pipeline (32 ch/wave); acc2 stays in
//                 REGISTERS through P6 (no LDS stash -- R16's stash raced
//                 and overlapped; removed entirely).
//   waves 8..11 : this block's ~100 expand rows in 4 chunks, placed in the
//                 inter-barrier gaps (co-resident by construction).
// 768 thr = 12 waves = 3 waves/EU; LDS 73.7KB -> 1 block/CU; VGPR budget
// ~170 >= 120 live. All __syncthreads unconditional at top level.
// ---------------------------------------------------------------------------
__global__ __launch_bounds__(768, 3) void fused_conv_x(
    const float* __restrict__ x,
    const __hip_bfloat16* __restrict__ bt1,
    const __hip_bfloat16* __restrict__ bt2,
    const float* __restrict__ cb1, const float* __restrict__ g1, const float* __restrict__ be1,
    const float* __restrict__ cb2, const float* __restrict__ g2, const float* __restrict__ be2,
    const float* __restrict__ lw, const float* __restrict__ lb,
    float* __restrict__ reg_len,
    const int* __restrict__ src, float* __restrict__ expanded, int T)
{
    __shared__ __align__(16) unsigned char xt[68 * 512];  // x rows s0-2..s0+65
    __shared__ __align__(16) unsigned char yt[66 * 512];  // y rows s0-1..s0+64
    __shared__ float red[66][17];  // sum at w*2, sumsq at w*2+1; gcd(17,32)=1
    __shared__ float stats[66][2];

    const int tid = threadIdx.x;
    const int b = blockIdx.y;
    const int s0 = blockIdx.x * 64;

    const int lane = tid & 63;
    const int wid = tid >> 6;   // 0..11
    const int l15 = lane & 15;
    const int lk = lane >> 4;
    const int fbase = (wid & 7) * 32;

    // ---- expand work assignment (waves 8..11) ----
    const int nrows = 16 * T;
    const int rpb = (nrows + 255) >> 8;          // rows per block (~100)
    const int rpw = (rpb + 3) >> 2;              // rows per expand wave (~25)
    const int csz = (rpw + 3) >> 2;              // rows per chunk (~7)
    const int erow0 = (b * 16 + blockIdx.x) * rpb + (wid - 8) * rpw;

    auto expand_chunk = [&](int c) {
        const int i0 = c * csz;
        const int i1 = (i0 + csz < rpw) ? i0 + csz : rpw;
        for (int i = i0; i < i1; ++i) {
            const int row = erow0 + i;
            if (row < nrows) {
                const int bb = row / T;
                const int s = src[row];
                float4 val = make_float4(0.f, 0.f, 0.f, 0.f);
                if (s >= 0)
                    val = *(const float4*)(x + ((size_t)(bb * SLEN + s)) * CDIM + lane * 4);
                *(float4*)(expanded + (size_t)row * CDIM + lane * 4) = val;
            }
        }
    };

    // ---- conv B pointers ----
    const __hip_bfloat16* p10 = bt1 + (size_t)(fbase + l15) * KTOT + lk * 8;
    const __hip_bfloat16* p11 = p10 + 16 * KTOT;
    const __hip_bfloat16* p20 = bt2 + (size_t)(fbase + l15) * KTOT + lk * 8;
    const __hip_bfloat16* p21 = p20 + 16 * KTOT;

    frag_ab pb0[PD], pb1[PD];
    if (wid < 8) {
#pragma unroll
        for (int i = 0; i < PD; ++i) {
            pb0[i] = *(const frag_ab*)(p10 + i * 32);
            pb1[i] = *(const frag_ab*)(p11 + i * 32);
        }
    }

    // ---- stage x rows s0-2 .. s0+65 as swizzled bf16 [68][512B] (ALL waves)
    const float* xin = x + (size_t)b * SLEN * CDIM;
    for (int ii = tid; ii < 68 * 32; ii += 768) {
        const int r = ii >> 5, cc = ii & 31;
        const int s = s0 - 2 + r;
        frag_ab v = {0, 0, 0, 0, 0, 0, 0, 0};
        if (s >= 0 && s < SLEN) {
            const float4* p = (const float4*)(xin + (size_t)s * CDIM + cc * 8);
            const float4 q0 = p[0], q1 = p[1];
            v[0] = f2bf(q0.x); v[1] = f2bf(q0.y); v[2] = f2bf(q0.z); v[3] = f2bf(q0.w);
            v[4] = f2bf(q1.x); v[5] = f2bf(q1.y); v[6] = f2bf(q1.z); v[7] = f2bf(q1.w);
        }
        *(frag_ab*)(xt + r * 512 + ((cc * 16) ^ ((r & 7) << 4))) = v;
    }
    __syncthreads();  // (1) xt ready

    // ========== P1: conv1 K-loop + conv2 ring + LN1 partials | expand c0 ===
    frag_cd acc1[5][2];
    frag_cd acc2[4][2];   // function scope: lives in registers through P6
    frag_ab qb0[PD], qb1[PD];
    if (wid < 8) {
#pragma unroll
        for (int mf = 0; mf < 5; ++mf) {
            acc1[mf][0] = {0.f, 0.f, 0.f, 0.f};
            acc1[mf][1] = {0.f, 0.f, 0.f, 0.f};
        }
#pragma unroll
        for (int kk = 0; kk < 24; ++kk) {
            const frag_ab bb0 = pb0[kk % PD];
            const frag_ab bb1 = pb1[kk % PD];
            if (kk + PD < 24) {
                pb0[kk % PD] = *(const frag_ab*)(p10 + (kk + PD) * 32);
                pb1[kk % PD] = *(const frag_ab*)(p11 + (kk + PD) * 32);
            }
            const int k3 = kk >> 3;
            const int colbyte = (kk & 7) * 64 + lk * 16;
            frag_ab a[5];
#pragma unroll
            for (int mf = 0; mf < 5; ++mf) {
                int r = mf * 16 + l15 + k3;
                if (mf == 4) r = (r > 67) ? 67 : r;  // rows >67 -> discarded outputs
                a[mf] = *(const frag_ab*)(xt + r * 512 + (colbyte ^ ((r & 7) << 4)));
            }
#pragma unroll
            for (int mf = 0; mf < 5; ++mf) {
                acc1[mf][0] = __builtin_amdgcn_mfma_f32_16x16x32_bf16(a[mf], bb0, acc1[mf][0], 0, 0, 0);
                acc1[mf][1] = __builtin_amdgcn_mfma_f32_16x16x32_bf16(a[mf], bb1, acc1[mf][1], 0, 0, 0);
            }
        }

        // conv2 B prefetch ring; latency hides under LN1 epilogue
#pragma unroll
        for (int i = 0; i < PD; ++i) {
            qb0[i] = *(const frag_ab*)(p20 + i * 32);
            qb1[i] = *(const frag_ab*)(p21 + i * 32);
        }

        // bias1 + LN1 row partials (single pass: sum + sumsq)
        const float bias0 = cb1[fbase + l15];
        const float bias1 = cb1[fbase + 16 + l15];
#pragma unroll
        for (int mf = 0; mf < 5; ++mf) {
#pragma unroll
            for (int j = 0; j < 4; ++j) {
                acc1[mf][0][j] += bias0;
                acc1[mf][1][j] += bias1;
                float p = acc1[mf][0][j] + acc1[mf][1][j];
                float q = acc1[mf][0][j] * acc1[mf][0][j] + acc1[mf][1][j] * acc1[mf][1][j];
#pragma unroll
                for (int m = 1; m < 16; m <<= 1) {
                    p += __shfl_xor(p, m);
                    q += __shfl_xor(q, m);
                }
                const bool valid = (mf < 4) || (lk == 0 && j < 2);
                if (l15 == 0 && valid) {
                    const int yr = mf * 16 + lk * 4 + j;  // 0..65
                    red[yr][wid * 2] = p;
                    red[yr][wid * 2 + 1] = q;
                }
            }
        }
    } else {
        expand_chunk(0);
    }
    __syncthreads();  // (2)
    if (tid < 66) {
        float s = 0.f, q = 0.f;
#pragma unroll
        for (int wv = 0; wv < 8; ++wv) { s += red[tid][wv * 2]; q += red[tid][wv * 2 + 1]; }
        const float mean = s * (1.f / 256.f);
        const float var = q * (1.f / 256.f) - mean * mean;
        stats[tid][0] = mean;
        stats[tid][1] = rsqrtf(var + 1e-5f);
    }
    __syncthreads();  // (3)

    // ========== P3: LN1+ReLU -> y tile | expand c1 ==========
    if (wid < 8) {
        const float ga0 = g1[fbase + l15], ga1 = g1[fbase + 16 + l15];
        const float bb0 = be1[fbase + l15], bb1 = be1[fbase + 16 + l15];
        const int c0b = (fbase + l15) * 2;
        const int c1b = (fbase + 16 + l15) * 2;
#pragma unroll
        for (int mf = 0; mf < 5; ++mf) {
#pragma unroll
            for (int j = 0; j < 4; ++j) {
                const bool valid = (mf < 4) || (lk == 0 && j < 2);
                if (valid) {
                    const int yr = mf * 16 + lk * 4 + j;
                    const float mean = stats[yr][0], rs = stats[yr][1];
                    float v0 = fmaxf((acc1[mf][0][j] - mean) * rs * ga0 + bb0, 0.f);
                    float v1 = fmaxf((acc1[mf][1][j] - mean) * rs * ga1 + bb1, 0.f);
                    const bool zrow = (blockIdx.x == 0 && yr == 0) ||
                                      (blockIdx.x == 15 && yr == 65);
                    if (zrow) { v0 = 0.f; v1 = 0.f; }
                    const int sw = (yr & 7) << 4;
                    *(short*)(yt + yr * 512 + (c0b ^ sw)) = f2bf(v0);
                    *(short*)(yt + yr * 512 + (c1b ^ sw)) = f2bf(v1);
                }
            }
        }
    } else {
        expand_chunk(1);
    }
    __syncthreads();  // (4) yt ready

    // ========== P4: conv2 K-loop + LN2 partials | expand c2 ==========
    if (wid < 8) {
#pragma unroll
        for (int mf = 0; mf < 4; ++mf) {
            acc2[mf][0] = {0.f, 0.f, 0.f, 0.f};
            acc2[mf][1] = {0.f, 0.f, 0.f, 0.f};
        }
#pragma unroll
        for (int kk = 0; kk < 24; ++kk) {
            const frag_ab bb0 = qb0[kk % PD];
            const frag_ab bb1 = qb1[kk % PD];
            if (kk + PD < 24) {
                qb0[kk % PD] = *(const frag_ab*)(p20 + (kk + PD) * 32);
                qb1[kk % PD] = *(const frag_ab*)(p21 + (kk + PD) * 32);
            }
            const int k3 = kk >> 3;
            const int colbyte = (kk & 7) * 64 + lk * 16;
            frag_ab a[4];
#pragma unroll
            for (int mf = 0; mf < 4; ++mf) {
                const int r = mf * 16 + l15 + k3;  // <= 65
                a[mf] = *(const frag_ab*)(yt + r * 512 + (colbyte ^ ((r & 7) << 4)));
            }
#pragma unroll
            for (int mf = 0; mf < 4; ++mf) {
                acc2[mf][0] = __builtin_amdgcn_mfma_f32_16x16x32_bf16(a[mf], bb0, acc2[mf][0], 0, 0, 0);
                acc2[mf][1] = __builtin_amdgcn_mfma_f32_16x16x32_bf16(a[mf], bb1, acc2[mf][1], 0, 0, 0);
            }
        }

        // bias2 + LN2 partials
        const float bias0 = cb2[fbase + l15];
        const float bias1 = cb2[fbase + 16 + l15];
#pragma unroll
        for (int mf = 0; mf < 4; ++mf) {
#pragma unroll
            for (int j = 0; j < 4; ++j) {
                acc2[mf][0][j] += bias0;
                acc2[mf][1][j] += bias1;
                float p = acc2[mf][0][j] + acc2[mf][1][j];
                float q = acc2[mf][0][j] * acc2[mf][0][j] + acc2[mf][1][j] * acc2[mf][1][j];
#pragma unroll
                for (int m = 1; m < 16; m <<= 1) {
                    p += __shfl_xor(p, m);
                    q += __shfl_xor(q, m);
                }
                if (l15 == 0) {
                    const int row = mf * 16 + lk * 4 + j;  // 0..63
                    red[row][wid * 2] = p;
                    red[row][wid * 2 + 1] = q;
                }
            }
        }
    } else {
        expand_chunk(2);
    }
    __syncthreads();  // (5)
    if (tid < 64) {
        float s = 0.f, q = 0.f;
#pragma unroll
        for (int wv = 0; wv < 8; ++wv) { s += red[tid][wv * 2]; q += red[tid][wv * 2 + 1]; }
        const float mean = s * (1.f / 256.f);
        const float var = q * (1.f / 256.f) - mean * mean;
        stats[tid][0] = mean;
        stats[tid][1] = rsqrtf(var + 1e-5f);
    }
    __syncthreads();  // (6)

    // ========== P6: LN2 + ReLU + linear dot (acc2 from registers) | c3 =====
    if (wid < 8) {
        const float ga0 = g2[fbase + l15], ga1 = g2[fbase + 16 + l15];
        const float bb0 = be2[fbase + l15], bb1 = be2[fbase + 16 + l15];
        const float lw0 = lw[fbase + l15], lw1 = lw[fbase + 16 + l15];
#pragma unroll
        for (int mf = 0; mf < 4; ++mf) {
#pragma unroll
            for (int j = 0; j < 4; ++j) {
                const int row = mf * 16 + lk * 4 + j;
                const float mean = stats[row][0], rs = stats[row][1];
                const float v0 = fmaxf((acc2[mf][0][j] - mean) * rs * ga0 + bb0, 0.f);
                const float v1 = fmaxf((acc2[mf][1][j] - mean) * rs * ga1 + bb1, 0.f);
                float p = v0 * lw0 + v1 * lw1;
#pragma unroll
                for (int m = 1; m < 16; m <<= 1) p += __shfl_xor(p, m);
                if (l15 == 0) red[row][wid * 2] = p;
            }
        }
    } else {
        expand_chunk(3);
    }
    __syncthreads();  // (7)
    if (tid < 64) {
        float s = 0.f;
#pragma unroll
        for (int wv = 0; wv < 8; ++wv) s += red[tid][wv * 2];
        reg_len[b * SLEN + s0 + tid] = fmaxf(s + lb[0], 0.f);
    }
}

// ---------------------------------------------------------------------------
extern "C" void kernel_launch(void* const* d_in, const int* in_sizes, int n_in,
                              void* d_out, int out_size, void* d_ws, size_t ws_size,
                              hipStream_t stream)
{
    const float* x       = (const float*)d_in[0];
    const float* target  = (const float*)d_in[1];
    const float* conv1_w = (const float*)d_in[2];
    const float* conv1_b = (const float*)d_in[3];
    const float* conv2_w = (const float*)d_in[4];
    const float* conv2_b = (const float*)d_in[5];
    const float* ln1_g   = (const float*)d_in[6];
    const float* ln1_b   = (const float*)d_in[7];
    const float* ln2_g   = (const float*)d_in[8];
    const float* ln2_b   = (const float*)d_in[9];
    const float* lin_w   = (const float*)d_in[10];
    const float* lin_b   = (const float*)d_in[11];

    const int B = 16, S = 1024, C = 256;
    const int T = (out_size - B * S) / (B * C);

    float* expanded = (float*)d_out;                      // (B, T, C)
    float* reg_len  = (float*)d_out + (size_t)B * T * C;  // (B, S)

    unsigned char* ws = (unsigned char*)d_ws;
    __hip_bfloat16* bt1 = (__hip_bfloat16*)ws;              // 384 KB
    __hip_bfloat16* bt2 = (__hip_bfloat16*)(ws + 393216);   // 384 KB
    int* src = (int*)(ws + 2 * 393216);                     // (B, T)

    scan_repack_kernel<<<400, 1024, 0, stream>>>(
        target, src, T, conv1_w, bt1, conv2_w, bt2);

    fused_conv_x<<<dim3(16, 16), 768, 0, stream>>>(
        x, bt1, bt2, conv1_b, ln1_g, ln1_b, conv2_b, ln2_g, ln2_b,
        lin_w, lin_b, reg_len, src, expanded, T);
}

// Round 18
// 54.101 us; speedup vs baseline: 1.2053x; 1.2053x over previous
//
#include <hip/hip_runtime.h>
#include <hip/hip_bf16.h>

using frag_ab = __attribute__((ext_vector_type(8))) short;  // 8 bf16
using frag_cd = __attribute__((ext_vector_type(4))) float;  // 4 fp32

#define SLEN 1024
#define CDIM 256
#define KTOT 768  // 3 * 256
#define PD 8      // B-fragment prefetch ring depth (proven: VGPR 120, no spill)

static __device__ __forceinline__ short f2bf(float f) {
    __hip_bfloat16 h = __float2bfloat16(f);
    return *reinterpret_cast<short*>(&h);
}

// ---------------------------------------------------------------------------
// Kernel 1: blocks 0..15: per-batch scan of d=round(target) -> src table;
//           blocks 16..399: repack both conv weights to Bt[f][k3*256+c] bf16
// ---------------------------------------------------------------------------
__global__ __launch_bounds__(1024) void scan_repack_kernel(
    const float* __restrict__ target, int* __restrict__ src, int T,
    const float* __restrict__ w1, __hip_bfloat16* __restrict__ bt1,
    const float* __restrict__ w2, __hip_bfloat16* __restrict__ bt2)
{
    __shared__ int waveSum[16];
    const int tid = threadIdx.x;

    if (blockIdx.x < 16) {
        const int b = blockIdx.x;
        for (int i = tid; i < T; i += 1024) src[b * T + i] = -1;

        const float tv = target[b * SLEN + tid];
        const int d = (int)rintf(tv);

        const int lane = tid & 63;
        const int wid = tid >> 6;
        int v = d;
#pragma unroll
        for (int off = 1; off < 64; off <<= 1) {
            int n = __shfl_up(v, off);
            if (lane >= off) v += n;
        }
        if (lane == 63) waveSum[wid] = v;
        __syncthreads();
        if (tid < 16) {
            int wv = waveSum[tid];
#pragma unroll
            for (int off = 1; off < 16; off <<= 1) {
                int n = __shfl_up(wv, off);
                if (tid >= off) wv += n;
            }
            waveSum[tid] = wv;
        }
        __syncthreads();
        const int fin = v + (wid > 0 ? waveSum[wid - 1] : 0);
        const int start = fin - d;
        for (int t = start; t < fin; ++t)
            if (t >= 0 && t < T) src[b * T + t] = tid;
    } else {
        const int id = (blockIdx.x - 16) * 1024 + tid;  // 0..393215
        const int which = id >= 196608;
        const int e = which ? id - 196608 : id;
        const int f = e / KTOT;
        const int K = e - f * KTOT;
        const int k3 = K >> 8;
        const int c = K & 255;
        const float* w = which ? w2 : w1;
        __hip_bfloat16* bt = which ? bt2 : bt1;
        bt[f * KTOT + K] = __float2bfloat16(w[f * KTOT + c * 3 + k3]);
    }
}

// ---------------------------------------------------------------------------
// Kernel 2: expanded[b,t,:] = (src>=0) ? x[b,src,:] : 0   (one wave per row)
// ---------------------------------------------------------------------------
__global__ __launch_bounds__(256) void expand_kernel(
    const float* __restrict__ x, const int* __restrict__ src,
    float* __restrict__ out, int T)
{
    const int row = blockIdx.x * 4 + (threadIdx.x >> 6);
    const int lane = threadIdx.x & 63;
    const int nrows = 16 * T;
    if (row >= nrows) return;
    const int b = row / T;
    const int s = src[row];
    float4 val = make_float4(0.f, 0.f, 0.f, 0.f);
    if (s >= 0)
        val = *(const float4*)(x + ((size_t)(b * SLEN + s)) * CDIM + lane * 4);
    *(float4*)(out + (size_t)row * CDIM + lane * 4) = val;
}

// ---------------------------------------------------------------------------
// Kernel 3: FUSED conv1+LN1+ReLU+conv2+LN2+ReLU+linear -> reg_len
// Empirical optimum across 17 rounds: 64-row tile, grid 256 = 1 block/CU,
// 512 thr = 8 waves, each wave owns 32 output channels; B streamed from L2
// ONCE per block (768 KB -- duplicating costs ~35%: R5/R6). VGPR 120, no
// spill -- the ONLY non-spilling tier on this compiler is (512 thr, 2
// waves/EU); every >2-wave/EU request (R5/R8/R10/R14/R17) halved the VGPR
// budget below the ~120 live set and spilled to scratch.
// ---------------------------------------------------------------------------
__global__ __launch_bounds__(512, 2) void fused_conv(
    const float* __restrict__ x,
    const __hip_bfloat16* __restrict__ bt1,
    const __hip_bfloat16* __restrict__ bt2,
    const float* __restrict__ cb1, const float* __restrict__ g1, const float* __restrict__ be1,
    const float* __restrict__ cb2, const float* __restrict__ g2, const float* __restrict__ be2,
    const float* __restrict__ lw, const float* __restrict__ lb,
    float* __restrict__ reg_len)
{
    __shared__ __align__(16) unsigned char xt[68 * 512];  // x rows s0-2..s0+65
    __shared__ __align__(16) unsigned char yt[66 * 512];  // y rows s0-1..s0+64
    __shared__ float red[66][17];  // sum at w*2, sumsq at w*2+1; gcd(17,32)=1
    __shared__ float stats[66][2];

    const int tid = threadIdx.x;
    const int b = blockIdx.y;
    const int s0 = blockIdx.x * 64;

    const int lane = tid & 63;
    const int wid = tid >> 6;   // 0..7
    const int l15 = lane & 15;
    const int lk = lane >> 4;
    const int fbase = wid * 32;

    // ---- conv1 B prefetch ring, issued before staging ----
    const __hip_bfloat16* p10 = bt1 + (size_t)(fbase + l15) * KTOT + lk * 8;
    const __hip_bfloat16* p11 = p10 + 16 * KTOT;
    frag_ab pb0[PD], pb1[PD];
#pragma unroll
    for (int i = 0; i < PD; ++i) {
        pb0[i] = *(const frag_ab*)(p10 + i * 32);
        pb1[i] = *(const frag_ab*)(p11 + i * 32);
    }

    // ---- stage x rows s0-2 .. s0+65 as swizzled bf16 [68][512B] ----
    const float* xin = x + (size_t)b * SLEN * CDIM;
    for (int ii = tid; ii < 68 * 32; ii += 512) {
        const int r = ii >> 5, cc = ii & 31;
        const int s = s0 - 2 + r;
        frag_ab v = {0, 0, 0, 0, 0, 0, 0, 0};
        if (s >= 0 && s < SLEN) {
            const float4* p = (const float4*)(xin + (size_t)s * CDIM + cc * 8);
            const float4 q0 = p[0], q1 = p[1];
            v[0] = f2bf(q0.x); v[1] = f2bf(q0.y); v[2] = f2bf(q0.z); v[3] = f2bf(q0.w);
            v[4] = f2bf(q1.x); v[5] = f2bf(q1.y); v[6] = f2bf(q1.z); v[7] = f2bf(q1.w);
        }
        *(frag_ab*)(xt + r * 512 + ((cc * 16) ^ ((r & 7) << 4))) = v;
    }
    __syncthreads();  // (1) xt ready

    // ========== conv1: y rows s0-1 .. s0+64 (66 rows, 5 frags) ==========
    frag_cd acc1[5][2];
#pragma unroll
    for (int mf = 0; mf < 5; ++mf) {
        acc1[mf][0] = {0.f, 0.f, 0.f, 0.f};
        acc1[mf][1] = {0.f, 0.f, 0.f, 0.f};
    }
#pragma unroll
    for (int kk = 0; kk < 24; ++kk) {
        const frag_ab bb0 = pb0[kk % PD];
        const frag_ab bb1 = pb1[kk % PD];
        if (kk + PD < 24) {
            pb0[kk % PD] = *(const frag_ab*)(p10 + (kk + PD) * 32);
            pb1[kk % PD] = *(const frag_ab*)(p11 + (kk + PD) * 32);
        }
        const int k3 = kk >> 3;
        const int colbyte = (kk & 7) * 64 + lk * 16;
        frag_ab a[5];
#pragma unroll
        for (int mf = 0; mf < 5; ++mf) {
            int r = mf * 16 + l15 + k3;
            if (mf == 4) r = (r > 67) ? 67 : r;  // rows >67 feed discarded outputs
            a[mf] = *(const frag_ab*)(xt + r * 512 + (colbyte ^ ((r & 7) << 4)));
        }
#pragma unroll
        for (int mf = 0; mf < 5; ++mf) {
            acc1[mf][0] = __builtin_amdgcn_mfma_f32_16x16x32_bf16(a[mf], bb0, acc1[mf][0], 0, 0, 0);
            acc1[mf][1] = __builtin_amdgcn_mfma_f32_16x16x32_bf16(a[mf], bb1, acc1[mf][1], 0, 0, 0);
        }
    }

    // ---- conv2 B prefetch ring; latency hides under LN1 epilogue ----
    const __hip_bfloat16* p20 = bt2 + (size_t)(fbase + l15) * KTOT + lk * 8;
    const __hip_bfloat16* p21 = p20 + 16 * KTOT;
    frag_ab qb0[PD], qb1[PD];
#pragma unroll
    for (int i = 0; i < PD; ++i) {
        qb0[i] = *(const frag_ab*)(p20 + i * 32);
        qb1[i] = *(const frag_ab*)(p21 + i * 32);
    }

    // ---- bias1 + LN1 row stats (rows yr = 0..65), single pass ----
    {
        const float bias0 = cb1[fbase + l15];
        const float bias1 = cb1[fbase + 16 + l15];
#pragma unroll
        for (int mf = 0; mf < 5; ++mf) {
#pragma unroll
            for (int j = 0; j < 4; ++j) {
                acc1[mf][0][j] += bias0;
                acc1[mf][1][j] += bias1;
                float p = acc1[mf][0][j] + acc1[mf][1][j];
                float q = acc1[mf][0][j] * acc1[mf][0][j] + acc1[mf][1][j] * acc1[mf][1][j];
#pragma unroll
                for (int m = 1; m < 16; m <<= 1) {
                    p += __shfl_xor(p, m);
                    q += __shfl_xor(q, m);
                }
                const bool valid = (mf < 4) || (lk == 0 && j < 2);
                if (l15 == 0 && valid) {
                    const int yr = mf * 16 + lk * 4 + j;  // 0..65
                    red[yr][wid * 2] = p;
                    red[yr][wid * 2 + 1] = q;
                }
            }
        }
    }
    __syncthreads();  // (2)
    if (tid < 66) {
        float s = 0.f, q = 0.f;
#pragma unroll
        for (int wv = 0; wv < 8; ++wv) { s += red[tid][wv * 2]; q += red[tid][wv * 2 + 1]; }
        const float mean = s * (1.f / 256.f);
        const float var = q * (1.f / 256.f) - mean * mean;
        stats[tid][0] = mean;
        stats[tid][1] = rsqrtf(var + 1e-5f);
    }
    __syncthreads();  // (3)

    // ---- LN1+ReLU -> y tile (bf16, swizzled); boundary rows zeroed ----
    {
        const float ga0 = g1[fbase + l15], ga1 = g1[fbase + 16 + l15];
        const float bb0 = be1[fbase + l15], bb1 = be1[fbase + 16 + l15];
        const int c0b = (fbase + l15) * 2;
        const int c1b = (fbase + 16 + l15) * 2;
#pragma unroll
        for (int mf = 0; mf < 5; ++mf) {
#pragma unroll
            for (int j = 0; j < 4; ++j) {
                const bool valid = (mf < 4) || (lk == 0 && j < 2);
                if (valid) {
                    const int yr = mf * 16 + lk * 4 + j;
                    const float mean = stats[yr][0], rs = stats[yr][1];
                    float v0 = fmaxf((acc1[mf][0][j] - mean) * rs * ga0 + bb0, 0.f);
                    float v1 = fmaxf((acc1[mf][1][j] - mean) * rs * ga1 + bb1, 0.f);
                    const bool zrow = (blockIdx.x == 0 && yr == 0) ||
                                      (blockIdx.x == 15 && yr == 65);
                    if (zrow) { v0 = 0.f; v1 = 0.f; }
                    const int sw = (yr & 7) << 4;
                    *(short*)(yt + yr * 512 + (c0b ^ sw)) = f2bf(v0);
                    *(short*)(yt + yr * 512 + (c1b ^ sw)) = f2bf(v1);
                }
            }
        }
    }
    __syncthreads();  // (4) yt ready

    // ========== conv2 on y tile (64 output rows, 4 frags) ==========
    frag_cd acc2[4][2];
#pragma unroll
    for (int mf = 0; mf < 4; ++mf) {
        acc2[mf][0] = {0.f, 0.f, 0.f, 0.f};
        acc2[mf][1] = {0.f, 0.f, 0.f, 0.f};
    }
#pragma unroll
    for (int kk = 0; kk < 24; ++kk) {
        const frag_ab bb0 = qb0[kk % PD];
        const frag_ab bb1 = qb1[kk % PD];
        if (kk + PD < 24) {
            qb0[kk % PD] = *(const frag_ab*)(p20 + (kk + PD) * 32);
            qb1[kk % PD] = *(const frag_ab*)(p21 + (kk + PD) * 32);
        }
        const int k3 = kk >> 3;
        const int colbyte = (kk & 7) * 64 + lk * 16;
        frag_ab a[4];
#pragma unroll
        for (int mf = 0; mf < 4; ++mf) {
            const int r = mf * 16 + l15 + k3;  // <= 65
            a[mf] = *(const frag_ab*)(yt + r * 512 + (colbyte ^ ((r & 7) << 4)));
        }
#pragma unroll
        for (int mf = 0; mf < 4; ++mf) {
            acc2[mf][0] = __builtin_amdgcn_mfma_f32_16x16x32_bf16(a[mf], bb0, acc2[mf][0], 0, 0, 0);
            acc2[mf][1] = __builtin_amdgcn_mfma_f32_16x16x32_bf16(a[mf], bb1, acc2[mf][1], 0, 0, 0);
        }
    }

    // ---- bias2 + LN2 stats (rows 0..63) ----
    {
        const float bias0 = cb2[fbase + l15];
        const float bias1 = cb2[fbase + 16 + l15];
#pragma unroll
        for (int mf = 0; mf < 4; ++mf) {
#pragma unroll
            for (int j = 0; j < 4; ++j) {
                acc2[mf][0][j] += bias0;
                acc2[mf][1][j] += bias1;
                float p = acc2[mf][0][j] + acc2[mf][1][j];
                float q = acc2[mf][0][j] * acc2[mf][0][j] + acc2[mf][1][j] * acc2[mf][1][j];
#pragma unroll
                for (int m = 1; m < 16; m <<= 1) {
                    p += __shfl_xor(p, m);
                    q += __shfl_xor(q, m);
                }
                if (l15 == 0) {
                    const int row = mf * 16 + lk * 4 + j;  // 0..63
                    red[row][wid * 2] = p;
                    red[row][wid * 2 + 1] = q;
                }
            }
        }
    }
    __syncthreads();  // (5)
    if (tid < 64) {
        float s = 0.f, q = 0.f;
#pragma unroll
        for (int wv = 0; wv < 8; ++wv) { s += red[tid][wv * 2]; q += red[tid][wv * 2 + 1]; }
        const float mean = s * (1.f / 256.f);
        const float var = q * (1.f / 256.f) - mean * mean;
        stats[tid][0] = mean;
        stats[tid][1] = rsqrtf(var + 1e-5f);
    }
    __syncthreads();  // (6)

    // ---- LN2 + ReLU + linear dot -> reg_len ----
    {
        const float ga0 = g2[fbase + l15], ga1 = g2[fbase + 16 + l15];
        const float bb0 = be2[fbase + l15], bb1 = be2[fbase + 16 + l15];
        const float lw0 = lw[fbase + l15], lw1 = lw[fbase + 16 + l15];
#pragma unroll
        for (int mf = 0; mf < 4; ++mf) {
#pragma unroll
            for (int j = 0; j < 4; ++j) {
                const int row = mf * 16 + lk * 4 + j;
                const float mean = stats[row][0], rs = stats[row][1];
                const float v0 = fmaxf((acc2[mf][0][j] - mean) * rs * ga0 + bb0, 0.f);
                const float v1 = fmaxf((acc2[mf][1][j] - mean) * rs * ga1 + bb1, 0.f);
                float p = v0 * lw0 + v1 * lw1;
#pragma unroll
                for (int m = 1; m < 16; m <<= 1) p += __shfl_xor(p, m);
                if (l15 == 0) red[row][wid * 2] = p;
            }
        }
    }
    __syncthreads();  // (7)
    if (tid < 64) {
        float s = 0.f;
#pragma unroll
        for (int wv = 0; wv < 8; ++wv) s += red[tid][wv * 2];
        reg_len[b * SLEN + s0 + tid] = fmaxf(s + lb[0], 0.f);
    }
}

// ---------------------------------------------------------------------------
extern "C" void kernel_launch(void* const* d_in, const int* in_sizes, int n_in,
                              void* d_out, int out_size, void* d_ws, size_t ws_size,
                              hipStream_t stream)
{
    const float* x       = (const float*)d_in[0];
    const float* target  = (const float*)d_in[1];
    const float* conv1_w = (const float*)d_in[2];
    const float* conv1_b = (const float*)d_in[3];
    const float* conv2_w = (const float*)d_in[4];
    const float* conv2_b = (const float*)d_in[5];
    const float* ln1_g   = (const float*)d_in[6];
    const float* ln1_b   = (const float*)d_in[7];
    const float* ln2_g   = (const float*)d_in[8];
    const float* ln2_b   = (const float*)d_in[9];
    const float* lin_w   = (const float*)d_in[10];
    const float* lin_b   = (const float*)d_in[11];

    const int B = 16, S = 1024, C = 256;
    const int T = (out_size - B * S) / (B * C);

    float* expanded = (float*)d_out;                      // (B, T, C)
    float* reg_len  = (float*)d_out + (size_t)B * T * C;  // (B, S)

    unsigned char* ws = (unsigned char*)d_ws;
    __hip_bfloat16* bt1 = (__hip_bfloat16*)ws;              // 384 KB
    __hip_bfloat16* bt2 = (__hip_bfloat16*)(ws + 393216);   // 384 KB
    int* src = (int*)(ws + 2 * 393216);                     // (B, T)

    scan_repack_kernel<<<400, 1024, 0, stream>>>(
        target, src, T, conv1_w, bt1, conv2_w, bt2);

    fused_conv<<<dim3(16, 16), 512, 0, stream>>>(
        x, bt1, bt2, conv1_b, ln1_g, ln1_b, conv2_b, ln2_g, ln2_b,
        lin_w, lin_b, reg_len);

    expand_kernel<<<(B * T + 3) / 4, 256, 0, stream>>>(x, src, expanded, T);
}